// Round 1
// baseline (91.855 us; speedup 1.0000x reference)
//
#include <hip/hip_runtime.h>

// GeneSymbolCNN: embed(67x32, pad0) -> conv1d k=2/3/4 (32ch each) + ReLU + max_t
//                -> concat(96) -> 96x96 linear + ReLU.
// Key transform: conv-over-embedding factors into per-token tables:
//   T_{k,h}[v][c] = sum_e embed[v,e] * w_k[c,e,h]   (bias folded into h=0 table)
//   y_k[b,c,p]    = sum_h T_{k,h}[x[b,p+h]][c]
// ReLU(max_p y) == max(0, max_p y). 9 tables of [67][32] f32, padded stride 36
// floats (keeps 16B alignment for float4 LDS reads, rotates bank groups for
// token-scattered accesses).

#define VOCABSZ 67
#define EMBSZ   32
#define NCH     32
#define NFEAT   96
#define SEQL    16
#define BATCH   131072
#define TSTR    36                    // padded floats per table row
#define VT      (VOCABSZ * TSTR)      // 2412 floats per table
#define NTAB    9
#define TABF    (NTAB * VT)           // 21708 floats = 86832 bytes

// ---------------- kernel 1: build the 9 per-token tables into d_ws ----------
__global__ __launch_bounds__(256) void build_tables(
    const float* __restrict__ embed,
    const float* __restrict__ w2, const float* __restrict__ b2,
    const float* __restrict__ w3, const float* __restrict__ b3,
    const float* __restrict__ w4, const float* __restrict__ b4,
    float* __restrict__ tabs)
{
    int idx = blockIdx.x * 256 + threadIdx.x;
    if (idx >= NTAB * VOCABSZ * NCH) return;
    int c = idx & 31;
    int t = idx >> 5;            // 0..602 = j*67 + v
    int j = t / VOCABSZ;
    int v = t - j * VOCABSZ;

    const float* w; const float* bias; int k, h;
    if (j < 2)      { w = w2; k = 2; h = j;     bias = (h == 0) ? b2 : nullptr; }
    else if (j < 5) { w = w3; k = 3; h = j - 2; bias = (h == 0) ? b3 : nullptr; }
    else            { w = w4; k = 4; h = j - 5; bias = (h == 0) ? b4 : nullptr; }

    float acc = bias ? bias[c] : 0.0f;
    if (v != 0) {                 // padding_idx=0: embedding row 0 is zero
        #pragma unroll
        for (int e = 0; e < EMBSZ; ++e)
            acc += embed[v * EMBSZ + e] * w[(c * EMBSZ + e) * k + h];
    }
    tabs[(j * VOCABSZ + v) * TSTR + c] = acc;
}

// ---------------- kernel 2: fused conv-as-lookup + max + projection ---------
__global__ __launch_bounds__(512) void fused_cnn(
    const int*   __restrict__ x,
    const float* __restrict__ tabs,
    const float* __restrict__ pw,
    const float* __restrict__ pb,
    float*       __restrict__ out)
{
    extern __shared__ __align__(16) float lds[];
    const int tid = threadIdx.x;
    for (int i = tid; i < TABF; i += 512) lds[i] = tabs[i];
    __syncthreads();

    const int row = blockIdx.x * 512 + tid;     // grid is exact: 256*512 = B

    const int4* xp = reinterpret_cast<const int4*>(x + row * SEQL);
    int4 q0 = xp[0], q1 = xp[1], q2 = xp[2], q3 = xp[3];
    int voff[16];
    voff[ 0] = q0.x * TSTR; voff[ 1] = q0.y * TSTR; voff[ 2] = q0.z * TSTR; voff[ 3] = q0.w * TSTR;
    voff[ 4] = q1.x * TSTR; voff[ 5] = q1.y * TSTR; voff[ 6] = q1.z * TSTR; voff[ 7] = q1.w * TSTR;
    voff[ 8] = q2.x * TSTR; voff[ 9] = q2.y * TSTR; voff[10] = q2.z * TSTR; voff[11] = q2.w * TSTR;
    voff[12] = q3.x * TSTR; voff[13] = q3.y * TSTR; voff[14] = q3.z * TSTR; voff[15] = q3.w * TSTR;

    float m2[NCH], m3[NCH], m4[NCH];
    #pragma unroll
    for (int c = 0; c < NCH; ++c) { m2[c] = 0.f; m3[c] = 0.f; m4[c] = 0.f; }

    // conv2: tables 0,1 over 15 positions
    #pragma unroll
    for (int p = 0; p < 15; ++p) {
        const float* a0 = lds + 0 * VT + voff[p];
        const float* a1 = lds + 1 * VT + voff[p + 1];
        #pragma unroll
        for (int q = 0; q < 8; ++q) {
            float4 u = *reinterpret_cast<const float4*>(a0 + q * 4);
            float4 w = *reinterpret_cast<const float4*>(a1 + q * 4);
            m2[q*4+0] = fmaxf(m2[q*4+0], u.x + w.x);
            m2[q*4+1] = fmaxf(m2[q*4+1], u.y + w.y);
            m2[q*4+2] = fmaxf(m2[q*4+2], u.z + w.z);
            m2[q*4+3] = fmaxf(m2[q*4+3], u.w + w.w);
        }
    }
    // conv3: tables 2,3,4 over 14 positions
    #pragma unroll
    for (int p = 0; p < 14; ++p) {
        const float* a0 = lds + 2 * VT + voff[p];
        const float* a1 = lds + 3 * VT + voff[p + 1];
        const float* a2 = lds + 4 * VT + voff[p + 2];
        #pragma unroll
        for (int q = 0; q < 8; ++q) {
            float4 u = *reinterpret_cast<const float4*>(a0 + q * 4);
            float4 w = *reinterpret_cast<const float4*>(a1 + q * 4);
            float4 s = *reinterpret_cast<const float4*>(a2 + q * 4);
            m3[q*4+0] = fmaxf(m3[q*4+0], u.x + w.x + s.x);
            m3[q*4+1] = fmaxf(m3[q*4+1], u.y + w.y + s.y);
            m3[q*4+2] = fmaxf(m3[q*4+2], u.z + w.z + s.z);
            m3[q*4+3] = fmaxf(m3[q*4+3], u.w + w.w + s.w);
        }
    }
    // conv4: tables 5,6,7,8 over 13 positions
    #pragma unroll
    for (int p = 0; p < 13; ++p) {
        const float* a0 = lds + 5 * VT + voff[p];
        const float* a1 = lds + 6 * VT + voff[p + 1];
        const float* a2 = lds + 7 * VT + voff[p + 2];
        const float* a3 = lds + 8 * VT + voff[p + 3];
        #pragma unroll
        for (int q = 0; q < 8; ++q) {
            float4 u = *reinterpret_cast<const float4*>(a0 + q * 4);
            float4 w = *reinterpret_cast<const float4*>(a1 + q * 4);
            float4 s = *reinterpret_cast<const float4*>(a2 + q * 4);
            float4 r = *reinterpret_cast<const float4*>(a3 + q * 4);
            m4[q*4+0] = fmaxf(m4[q*4+0], u.x + w.x + s.x + r.x);
            m4[q*4+1] = fmaxf(m4[q*4+1], u.y + w.y + s.y + r.y);
            m4[q*4+2] = fmaxf(m4[q*4+2], u.z + w.z + s.z + r.z);
            m4[q*4+3] = fmaxf(m4[q*4+3], u.w + w.w + s.w + r.w);
        }
    }

    // projection: out[row,o] = relu(sum_f feat[f]*pw[o,f] + pb[o])
    // pw/pb indices are wave-uniform -> scalar loads, v_fmac with SGPR src.
    float* orow = out + (size_t)row * NFEAT;
    #pragma unroll 1
    for (int ob = 0; ob < NFEAT; ob += 8) {
        float acc[8];
        #pragma unroll
        for (int k = 0; k < 8; ++k) acc[k] = pb[ob + k];
        #pragma unroll
        for (int f = 0; f < NFEAT; ++f) {
            float fv = (f < 32) ? m2[f] : ((f < 64) ? m3[f - 32] : m4[f - 64]);
            #pragma unroll
            for (int k = 0; k < 8; ++k) acc[k] += fv * pw[(ob + k) * NFEAT + f];
        }
        float4 o0 = make_float4(fmaxf(acc[0], 0.f), fmaxf(acc[1], 0.f),
                                fmaxf(acc[2], 0.f), fmaxf(acc[3], 0.f));
        float4 o1 = make_float4(fmaxf(acc[4], 0.f), fmaxf(acc[5], 0.f),
                                fmaxf(acc[6], 0.f), fmaxf(acc[7], 0.f));
        *reinterpret_cast<float4*>(orow + ob)     = o0;
        *reinterpret_cast<float4*>(orow + ob + 4) = o1;
    }
}

extern "C" void kernel_launch(void* const* d_in, const int* in_sizes, int n_in,
                              void* d_out, int out_size, void* d_ws, size_t ws_size,
                              hipStream_t stream)
{
    const int*   x     = (const int*)  d_in[0];
    const float* embed = (const float*)d_in[1];
    const float* w2    = (const float*)d_in[2];
    const float* b2    = (const float*)d_in[3];
    const float* w3    = (const float*)d_in[4];
    const float* b3    = (const float*)d_in[5];
    const float* w4    = (const float*)d_in[6];
    const float* b4    = (const float*)d_in[7];
    const float* pw    = (const float*)d_in[8];
    const float* pb    = (const float*)d_in[9];
    float* out  = (float*)d_out;
    float* tabs = (float*)d_ws;           // 86832 bytes of scratch

    build_tables<<<(NTAB * VOCABSZ * NCH + 255) / 256, 256, 0, stream>>>(
        embed, w2, b2, w3, b3, w4, b4, tabs);

    // dynamic LDS 86832 B > 64 KB default: raise the cap (no-op if already set)
    (void)hipFuncSetAttribute((const void*)fused_cnn,
                              hipFuncAttributeMaxDynamicSharedMemorySize,
                              TABF * 4);
    fused_cnn<<<BATCH / 512, 512, TABF * 4, stream>>>(x, tabs, pw, pb, out);
}